// Round 1
// baseline (3725.206 us; speedup 1.0000x reference)
//
#include <hip/hip_runtime.h>
#include <math.h>

#define Bn 32
#define Cc 256
#define Hh 56
#define Ww 56
#define OT 32          // output channels per block
#define HT 4           // output rows per block
#define CCH 16         // input-channel chunk staged in LDS
#define NPB ((Hh / HT) * (Cc / OT))  // 14*8 = 112 blocks per image
#define NBLK (Bn * NPB)              // 3584

// ---------------- block-wide sum over 256 threads ----------------
__device__ __forceinline__ float block_sum(float v, float* red) {
#pragma unroll
    for (int off = 32; off > 0; off >>= 1) v += __shfl_down(v, off, 64);
    const int wv = threadIdx.x >> 6;
    __syncthreads();
    if ((threadIdx.x & 63) == 0) red[wv] = v;
    __syncthreads();
    return red[0] + red[1] + red[2] + red[3];
}

// ---------------- IR-Net weight binarization: bw = sign(w-mu)*scale ----------------
// per output channel o: mu = mean, sd = population std, scale = mean|w-mu| / (sd + 1e-5)
__global__ __launch_bounds__(256) void k_binarize(const float* __restrict__ w,
                                                  float* __restrict__ bw) {
    __shared__ float red[4];
    const int o = blockIdx.x;
    const float* wo = w + (size_t)o * 2304;
    float v[9];
    float s = 0.f, s2 = 0.f;
#pragma unroll
    for (int i = 0; i < 9; ++i) {
        v[i] = wo[threadIdx.x + 256 * i];
        s += v[i];
        s2 += v[i] * v[i];
    }
    s = block_sum(s, red);
    s2 = block_sum(s2, red);
    const float mu = s * (1.f / 2304.f);
    const float var = fmaxf(s2 * (1.f / 2304.f) - mu * mu, 0.f);
    const float sd = sqrtf(var);
    float sa = 0.f;
#pragma unroll
    for (int i = 0; i < 9; ++i) sa += fabsf(v[i] - mu);
    sa = block_sum(sa, red);
    const float scale = (sa * (1.f / 2304.f)) / (sd + 1e-5f);
    float* bo = bw + (size_t)o * 2304;
#pragma unroll
    for (int i = 0; i < 9; ++i) {
        const float d = v[i] - mu;
        const float sg = (d > 0.f) ? 1.f : ((d < 0.f) ? -1.f : 0.f);
        bo[threadIdx.x + 256 * i] = sg * scale;
    }
}

// ---------------- BN fold: out = [inv1(256), beta1(256), inv2(256), beta2(256)] ----------------
__global__ void k_bnfold(const float* __restrict__ g1, const float* __restrict__ b1,
                         const float* __restrict__ m1, const float* __restrict__ v1,
                         const float* __restrict__ g2, const float* __restrict__ b2,
                         const float* __restrict__ m2, const float* __restrict__ v2,
                         float* __restrict__ out) {
    const int i = threadIdx.x;
    const float i1 = g1[i] / sqrtf(v1[i] + 1e-5f);
    const float i2 = g2[i] / sqrtf(v2[i] + 1e-5f);
    out[i] = i1;
    out[256 + i] = b1[i] - m1[i] * i1;
    out[512 + i] = i2;
    out[768 + i] = b2[i] - m2[i] * i2;
}

// ---------------- LSQ 4-bit quantize x -> u8 codes, vectorized ----------------
__global__ __launch_bounds__(256) void k_quant4(const float4* __restrict__ x,
                                                uchar4* __restrict__ q,
                                                const float* __restrict__ ap, int n4) {
    const int i = blockIdx.x * 256 + threadIdx.x;
    if (i >= n4) return;
    const float a = ap[0];
    const float4 v = x[i];
    uchar4 o;
    o.x = (unsigned char)(int)rintf(fminf(fmaxf(v.x / a, 0.f), 15.f));
    o.y = (unsigned char)(int)rintf(fminf(fmaxf(v.y / a, 0.f), 15.f));
    o.z = (unsigned char)(int)rintf(fminf(fmaxf(v.z / a, 0.f), 15.f));
    o.w = (unsigned char)(int)rintf(fminf(fmaxf(v.w / a, 0.f), 15.f));
    q[i] = o;
}

// ---------------- direct 3x3 conv, pad 1, stride 1 ----------------
// input: u8 quant codes (dequant = code * a_in). output: QOUT ? u8 codes for next
// layer (BN+ReLU+LSQ fused) : fp32 BN+ReLU.
template <bool QOUT>
__global__ __launch_bounds__(256) void k_conv(const unsigned char* __restrict__ xq,
                                              const float* __restrict__ bw,
                                              const float* __restrict__ bnp,  // inv[256],beta[256]
                                              const float* __restrict__ a_in_p,
                                              const float* __restrict__ a_out_p,
                                              unsigned char* __restrict__ yq,
                                              float* __restrict__ yf) {
    __shared__ float xs[CCH][HT + 2][Ww + 2];  // 16*6*58*4 = 22272 B
    __shared__ float wsm[OT * 145];            // padded stride 145 -> conflict-free

    const int bid = blockIdx.x;
    const int hb = bid % (Hh / HT);
    const int ob = (bid / (Hh / HT)) % (Cc / OT);
    const int n = bid / NPB;
    const int h0 = hb * HT;
    const int oc0 = ob * OT;

    const int tid = threadIdx.x;
    const int ol = tid >> 3;        // 0..31 local output channel
    const int g = tid & 7;
    const int r = g >> 1;           // 0..3 output row in tile
    const int wh = (g & 1) * 28;    // column half

    const float a_in = a_in_p[0];

    float acc[28];
#pragma unroll
    for (int j = 0; j < 28; ++j) acc[j] = 0.f;

    const unsigned char* xn = xq + (size_t)n * Cc * Hh * Ww;

    for (int cc = 0; cc < Cc; cc += CCH) {
        // stage input patch (dequantized) with zero padding
        for (int i = tid; i < CCH * (HT + 2) * (Ww + 2); i += 256) {
            const int c = i / ((HT + 2) * (Ww + 2));
            const int rr = (i / (Ww + 2)) % (HT + 2);
            const int cw = i % (Ww + 2);
            const int hh = h0 - 1 + rr;
            const int wwp = cw - 1;
            float v = 0.f;
            if (hh >= 0 && hh < Hh && wwp >= 0 && wwp < Ww)
                v = (float)xn[((size_t)(cc + c) * Hh + hh) * Ww + wwp] * a_in;
            xs[c][rr][cw] = v;
        }
        // stage weights: wsm[o*145 + c*9 + k]
        for (int i = tid; i < OT * CCH * 9; i += 256) {
            const int o = i / (CCH * 9);
            const int ck = i % (CCH * 9);
            wsm[o * 145 + ck] = bw[((size_t)(oc0 + o) * Cc + cc) * 9 + ck];
        }
        __syncthreads();

#pragma unroll 1
        for (int c = 0; c < CCH; ++c) {
            float wk[9];
#pragma unroll
            for (int k = 0; k < 9; ++k) wk[k] = wsm[ol * 145 + c * 9 + k];
#pragma unroll
            for (int dh = 0; dh < 3; ++dh) {
                const float* xr = &xs[c][r + dh][wh];
                float x0 = xr[0], x1 = xr[1];
#pragma unroll
                for (int j = 0; j < 28; ++j) {
                    const float x2 = xr[j + 2];
                    acc[j] = fmaf(wk[dh * 3 + 0], x0,
                             fmaf(wk[dh * 3 + 1], x1,
                             fmaf(wk[dh * 3 + 2], x2, acc[j])));
                    x0 = x1;
                    x1 = x2;
                }
            }
        }
        __syncthreads();
    }

    // epilogue: BN + ReLU (+ fused LSQ quant for next layer)
    const int oc = oc0 + ol;
    const float inv = bnp[oc];
    const float beta = bnp[256 + oc];
    const size_t obase = (((size_t)n * Cc + oc) * Hh + (h0 + r)) * Ww + wh;
    if constexpr (QOUT) {
        const float an = a_out_p[0];
#pragma unroll
        for (int j = 0; j < 28; ++j) {
            const float t = fmaxf(acc[j] * inv + beta, 0.f);
            const float qv = fminf(t / an, 15.f);
            yq[obase + j] = (unsigned char)(int)rintf(qv);
        }
    } else {
#pragma unroll
        for (int j = 0; j < 28; ++j) {
            yf[obase + j] = fmaxf(acc[j] * inv + beta, 0.f);
        }
    }
}

extern "C" void kernel_launch(void* const* d_in, const int* in_sizes, int n_in,
                              void* d_out, int out_size, void* d_ws, size_t ws_size,
                              hipStream_t stream) {
    const float* x  = (const float*)d_in[0];
    const float* w1 = (const float*)d_in[1];
    const float* a1 = (const float*)d_in[2];
    const float* g1 = (const float*)d_in[3];
    const float* b1 = (const float*)d_in[4];
    const float* m1 = (const float*)d_in[5];
    const float* v1 = (const float*)d_in[6];
    const float* w2 = (const float*)d_in[7];
    const float* a2 = (const float*)d_in[8];
    const float* g2 = (const float*)d_in[9];
    const float* b2 = (const float*)d_in[10];
    const float* m2 = (const float*)d_in[11];
    const float* v2 = (const float*)d_in[12];

    // workspace layout (~56 MB total)
    float* bw1 = (float*)d_ws;                    // 589824 f
    float* bw2 = bw1 + 589824;                    // 589824 f
    float* bn  = bw2 + 589824;                    // 1024 f: inv1,beta1,inv2,beta2
    unsigned char* xq1 = (unsigned char*)(bn + 1024);   // 25690112 B
    unsigned char* hq  = xq1 + (size_t)25690112;         // 25690112 B

    const int nelem = Bn * Cc * Hh * Ww;          // 25690112
    const int n4 = nelem / 4;                     // 6422528

    k_binarize<<<256, 256, 0, stream>>>(w1, bw1);
    k_binarize<<<256, 256, 0, stream>>>(w2, bw2);
    k_bnfold<<<1, 256, 0, stream>>>(g1, b1, m1, v1, g2, b2, m2, v2, bn);
    k_quant4<<<(n4 + 255) / 256, 256, 0, stream>>>((const float4*)x, (uchar4*)xq1, a1, n4);

    // layer 1: reads u8 x-codes, writes u8 h-codes (BN+ReLU+LSQ(alpha2) fused)
    k_conv<true><<<NBLK, 256, 0, stream>>>(xq1, bw1, bn, a1, a2, hq, nullptr);
    // layer 2: reads u8 h-codes, writes fp32 output (BN+ReLU)
    k_conv<false><<<NBLK, 256, 0, stream>>>(hq, bw2, bn + 512, a2, nullptr, nullptr, (float*)d_out);
}

// Round 2
// 337.071 us; speedup vs baseline: 11.0517x; 11.0517x over previous
//
#include <hip/hip_runtime.h>
#include <math.h>

typedef int v4i __attribute__((ext_vector_type(4)));
typedef int v16i __attribute__((ext_vector_type(16)));

#define Bn 32
#define Cc 256
#define Hh 56
#define Ww 56
#define RS 14848            // act LDS row stride: 58 cols * 256 c
#define ACT_BYTES (3 * RS)  // 44544

// ---------------- block-wide sum over 256 threads ----------------
__device__ __forceinline__ float block_sum(float v, float* red) {
#pragma unroll
    for (int off = 32; off > 0; off >>= 1) v += __shfl_down(v, off, 64);
    const int wv = threadIdx.x >> 6;
    __syncthreads();
    if ((threadIdx.x & 63) == 0) red[wv] = v;
    __syncthreads();
    return red[0] + red[1] + red[2] + red[3];
}

// ---- IR-Net binarize + pack sign codes into MFMA-fragment-contiguous layout ----
// wf[(((tap*8 + c32)*8 + octile)*64 + lane)*16 + j]:
//   lane = (half<<5)|(oc&31), c = c32*32 + half*16 + j, octile = oc>>5
__global__ __launch_bounds__(256) void k_binpack(const float* __restrict__ w,
                                                 signed char* __restrict__ wf,
                                                 float* __restrict__ wsc) {
    __shared__ float red[4];
    const int o = blockIdx.x;
    const float* wo = w + (size_t)o * 2304;
    const int t = threadIdx.x;
    float v[9];
    float s = 0.f, s2 = 0.f;
#pragma unroll
    for (int i = 0; i < 9; ++i) {
        v[i] = wo[t * 9 + i];
        s += v[i];
        s2 += v[i] * v[i];
    }
    s = block_sum(s, red);
    s2 = block_sum(s2, red);
    const float mu = s * (1.f / 2304.f);
    const float sd = sqrtf(fmaxf(s2 * (1.f / 2304.f) - mu * mu, 0.f));
    float sa = 0.f;
#pragma unroll
    for (int i = 0; i < 9; ++i) sa += fabsf(v[i] - mu);
    sa = block_sum(sa, red);
    if (t == 0) wsc[o] = (sa * (1.f / 2304.f)) / (sd + 1e-5f);
    const int c = t, c32 = c >> 5, hf = (c >> 4) & 1, j = c & 15;
    const int lane = (hf << 5) | (o & 31), octile = o >> 5;
#pragma unroll
    for (int tap = 0; tap < 9; ++tap) {
        const float d = v[tap] - mu;
        const signed char sg = (d > 0.f) ? 1 : ((d < 0.f) ? -1 : 0);
        wf[(size_t)(((tap * 8 + c32) * 8 + octile) * 64 + lane) * 16 + j] = sg;
    }
}

// ---- epilogue params: ep = [f1(256), beta1(256), f2(256), beta2(256)] ----
// f = alpha_in * wscale[oc] * g/sqrt(v+eps); beta = b - m*inv
__global__ void k_prep(const float* __restrict__ g1, const float* __restrict__ b1,
                       const float* __restrict__ m1, const float* __restrict__ v1,
                       const float* __restrict__ g2, const float* __restrict__ b2,
                       const float* __restrict__ m2, const float* __restrict__ v2,
                       const float* __restrict__ a1p, const float* __restrict__ a2p,
                       const float* __restrict__ ws1, const float* __restrict__ ws2,
                       float* __restrict__ ep) {
    const int i = threadIdx.x;
    const float i1 = g1[i] / sqrtf(v1[i] + 1e-5f);
    const float i2 = g2[i] / sqrtf(v2[i] + 1e-5f);
    ep[i] = a1p[0] * ws1[i] * i1;
    ep[256 + i] = b1[i] - m1[i] * i1;
    ep[512 + i] = a2p[0] * ws2[i] * i2;
    ep[768 + i] = b2[i] - m2[i] * i2;
}

// ---- LSQ 4-bit quantize NCHW fp32 -> NHWC u8 codes (LDS transpose) ----
__global__ __launch_bounds__(256) void k_quant_nhwc(const float* __restrict__ x,
                                                    unsigned char* __restrict__ xq,
                                                    const float* __restrict__ ap) {
    __shared__ unsigned char q[3584];  // [w 56][c 64], dword-swizzled
    const int bid = blockIdx.x;
    const int cg = bid & 3;
    const int h = (bid >> 2) % Hh;
    const int n = bid / (4 * Hh);
    const float a = ap[0];
    const int c0 = cg * 64;
    for (int i = threadIdx.x; i < 3584; i += 256) {
        const int cl = i / 56;
        const int w = i - cl * 56;
        const float v = x[(((size_t)n * Cc + c0 + cl) * Hh + h) * Ww + w];
        const float xs = fminf(fmaxf(v / a, 0.f), 15.f);
        q[w * 64 + (((cl >> 2) ^ (w & 15)) << 2) + (cl & 3)] = (unsigned char)(int)rintf(xs);
    }
    __syncthreads();
    unsigned int* dst = (unsigned int*)xq + (((size_t)n * Hh + h) * Ww) * 64;
    for (int j = threadIdx.x; j < 896; j += 256) {
        const int w = j >> 4, d = j & 15;
        dst[w * 64 + cg * 16 + d] = *(unsigned int*)(q + w * 64 + ((d ^ (w & 15)) << 2));
    }
}

// ---- implicit-GEMM conv: i8 MFMA 32x32x32 ----
// block: 256 thr = 4 waves; tile = 256 oc x 64 m (one output row, 56 valid)
// wave g: oc [g*64, g*64+64), acc tiles [octile 2][mtile 2]
template <bool QOUT>
__global__ __launch_bounds__(256, 2) void k_conv(const unsigned char* __restrict__ xin,
                                                 const signed char* __restrict__ wf,
                                                 const float* __restrict__ ep,
                                                 const float* __restrict__ a2p,
                                                 unsigned char* __restrict__ hq,
                                                 float* __restrict__ yout) {
    __shared__ unsigned char sm[ACT_BYTES + 16384];  // acts + hbuf
    const int bid = blockIdx.x;
    const int n = bid / Hh;
    const int h = bid % Hh;
    const int tid = threadIdx.x;

    // ---- stage 3 input rows NHWC -> LDS, c4 chunks XOR-swizzled by col ----
    {
        const v4i zero = {0, 0, 0, 0};
        for (int s = tid; s < 3 * 58 * 16; s += 256) {
            const int r = s / 928;
            const int rem = s - r * 928;
            const int xc = rem >> 4;  // LDS col 0..57 (= input x + 1)
            const int c4 = rem & 15;
            const int y = h - 1 + r;
            const int xi = xc - 1;
            v4i v = zero;
            if ((unsigned)y < 56u && (unsigned)xi < 56u)
                v = ((const v4i*)xin)[((n * Hh + y) * Ww + xi) * 16 + c4];
            *(v4i*)(sm + r * RS + xc * 256 + ((c4 ^ (xc & 15)) << 4)) = v;
        }
    }
    __syncthreads();

    const int lane = tid & 63;
    const int g = tid >> 6;
    const int half = lane >> 5;
    const int lm = lane & 31;

    int cb[3][2], cm[3][2];
#pragma unroll
    for (int kw = 0; kw < 3; ++kw)
#pragma unroll
        for (int mt = 0; mt < 2; ++mt) {
            int col = mt * 32 + lm + kw;  // input x + 1
            col = col > 57 ? 57 : col;    // clamp into zero-pad col (w>=56 is dead anyway)
            cb[kw][mt] = col * 256;
            cm[kw][mt] = col & 15;
        }

    v16i acc00 = {}, acc01 = {}, acc10 = {}, acc11 = {};
    const v4i* wp = (const v4i*)wf;

    for (int kh = 0; kh < 3; ++kh) {
        const unsigned char* rowp = sm + kh * RS;
#pragma unroll
        for (int kw = 0; kw < 3; ++kw) {
            const int tap = kh * 3 + kw;
            const unsigned char* b0p = rowp + cb[kw][0];
            const unsigned char* b1p = rowp + cb[kw][1];
            const int x0 = cm[kw][0], x1 = cm[kw][1];
#pragma unroll
            for (int c32 = 0; c32 < 8; ++c32) {
                const int fb = (tap * 8 + c32) * 8 + g * 2;
                const v4i A0 = wp[fb * 64 + lane];
                const v4i A1 = wp[(fb + 1) * 64 + lane];
                const int c4 = c32 * 2 + half;
                const v4i B0 = *(const v4i*)(b0p + ((c4 ^ x0) << 4));
                const v4i B1 = *(const v4i*)(b1p + ((c4 ^ x1) << 4));
                acc00 = __builtin_amdgcn_mfma_i32_32x32x32_i8(A0, B0, acc00, 0, 0, 0);
                acc01 = __builtin_amdgcn_mfma_i32_32x32x32_i8(A0, B1, acc01, 0, 0, 0);
                acc10 = __builtin_amdgcn_mfma_i32_32x32x32_i8(A1, B0, acc10, 0, 0, 0);
                acc11 = __builtin_amdgcn_mfma_i32_32x32x32_i8(A1, B1, acc11, 0, 0, 0);
            }
        }
    }

    // ---- epilogue: BN + ReLU (+ LSQ quant to u8 NHWC for layer 1) ----
    if constexpr (QOUT) {
        const float inva = 1.0f / a2p[0];
        unsigned char* hbuf = sm + ACT_BYTES;  // [w 64][oc 256] u8, dword-swizzled
#pragma unroll
        for (int ot = 0; ot < 2; ++ot) {
            const int ocb = g * 64 + ot * 32 + half * 4;
#pragma unroll
            for (int mt = 0; mt < 2; ++mt) {
                const int w = mt * 32 + lm;
                if (w < 56) {
                    const v16i av = ot ? (mt ? acc11 : acc10) : (mt ? acc01 : acc00);
#pragma unroll
                    for (int rg = 0; rg < 4; ++rg) {
                        const int oc0 = ocb + rg * 8;
                        unsigned int pk = 0;
#pragma unroll
                        for (int q = 0; q < 4; ++q) {
                            const int oc = oc0 + q;
                            const float t0 = fmaf((float)av[rg * 4 + q], ep[oc], ep[256 + oc]);
                            const float t = fmaxf(t0, 0.f);
                            const float xs = fminf(t * inva, 15.f);
                            pk |= ((unsigned int)(int)rintf(xs)) << (8 * q);
                        }
                        const int dwi = oc0 >> 2;
                        *(unsigned int*)(hbuf + w * 256 + ((dwi ^ ((w & 15) << 2)) << 2)) = pk;
                    }
                }
            }
        }
        __syncthreads();
        unsigned int* dst = (unsigned int*)hq + (((size_t)n * Hh + h) * Ww) * 64;
        for (int j = tid; j < 56 * 64; j += 256) {
            const int w = j >> 6, dw = j & 63;
            dst[j] = *(unsigned int*)(hbuf + w * 256 + ((dw ^ ((w & 15) << 2)) << 2));
        }
    } else {
        float* dst = yout + (size_t)n * Cc * 3136 + (size_t)h * 56;
#pragma unroll
        for (int ot = 0; ot < 2; ++ot) {
#pragma unroll
            for (int mt = 0; mt < 2; ++mt) {
                const int w = mt * 32 + lm;
                if (w < 56) {
                    const v16i av = ot ? (mt ? acc11 : acc10) : (mt ? acc01 : acc00);
#pragma unroll
                    for (int r = 0; r < 16; ++r) {
                        const int oc = g * 64 + ot * 32 + (r & 3) + 8 * (r >> 2) + 4 * half;
                        const float y = fmaxf(fmaf((float)av[r], ep[oc], ep[256 + oc]), 0.f);
                        dst[(size_t)oc * 3136 + w] = y;
                    }
                }
            }
        }
    }
}

extern "C" void kernel_launch(void* const* d_in, const int* in_sizes, int n_in,
                              void* d_out, int out_size, void* d_ws, size_t ws_size,
                              hipStream_t stream) {
    const float* x = (const float*)d_in[0];
    const float* w1 = (const float*)d_in[1];
    const float* a1 = (const float*)d_in[2];
    const float* g1 = (const float*)d_in[3];
    const float* b1 = (const float*)d_in[4];
    const float* m1 = (const float*)d_in[5];
    const float* v1 = (const float*)d_in[6];
    const float* w2 = (const float*)d_in[7];
    const float* a2 = (const float*)d_in[8];
    const float* g2 = (const float*)d_in[9];
    const float* b2 = (const float*)d_in[10];
    const float* m2 = (const float*)d_in[11];
    const float* v2 = (const float*)d_in[12];

    // workspace layout (~52.6 MB)
    signed char* wf1 = (signed char*)d_ws;        // 589824 B
    signed char* wf2 = wf1 + 589824;              // 589824 B
    float* wsc1 = (float*)(wf2 + 589824);         // 256 f
    float* wsc2 = wsc1 + 256;                     // 256 f
    float* ep = wsc2 + 256;                       // 1024 f
    unsigned char* xq1 = (unsigned char*)(ep + 1024);  // 25690112 B (NHWC u8)
    unsigned char* hq = xq1 + (size_t)25690112;         // 25690112 B (NHWC u8)

    k_binpack<<<256, 256, 0, stream>>>(w1, wf1, wsc1);
    k_binpack<<<256, 256, 0, stream>>>(w2, wf2, wsc2);
    k_prep<<<1, 256, 0, stream>>>(g1, b1, m1, v1, g2, b2, m2, v2, a1, a2, wsc1, wsc2, ep);
    k_quant_nhwc<<<Bn * Hh * 4, 256, 0, stream>>>(x, xq1, a1);

    // layer 1: u8 NHWC in -> u8 NHWC h-codes (BN+ReLU+LSQ(alpha2) fused)
    k_conv<true><<<Bn * Hh, 256, 0, stream>>>(xq1, wf1, ep, a2, hq, nullptr);
    // layer 2: u8 NHWC in -> fp32 NCHW out (BN+ReLU)
    k_conv<false><<<Bn * Hh, 256, 0, stream>>>(hq, wf2, ep + 512, nullptr, nullptr, (float*)d_out);
}

// Round 3
// 245.122 us; speedup vs baseline: 15.1974x; 1.3751x over previous
//
#include <hip/hip_runtime.h>
#include <math.h>

typedef int v4i __attribute__((ext_vector_type(4)));
typedef int v16i __attribute__((ext_vector_type(16)));
typedef unsigned long long u64;

#define Bn 32
#define Cc 256
#define Hh 56
#define Ww 56
#define CSTR 136            // LDS bytes per act col (128 packed + 8 pad -> 2-way banks)
#define RSTR (58 * CSTR)    // 7888 per act row
#define ACT_LDS (6 * RSTR)  // 47328

// ---------------- block-wide sum over 256 threads ----------------
__device__ __forceinline__ float block_sum(float v, float* red) {
#pragma unroll
    for (int off = 32; off > 0; off >>= 1) v += __shfl_down(v, off, 64);
    const int wv = threadIdx.x >> 6;
    __syncthreads();
    if ((threadIdx.x & 63) == 0) red[wv] = v;
    __syncthreads();
    return red[0] + red[1] + red[2] + red[3];
}

// ---- IR-Net binarize + pack sign codes into MFMA-fragment-contiguous layout ----
// v4i unit index: ((tap*8 + c32)*8 + octile)*64 + lane ; lane=(half<<5)|(oc&31)
__global__ __launch_bounds__(256) void k_binpack(const float* __restrict__ w,
                                                 signed char* __restrict__ wf,
                                                 float* __restrict__ wsc) {
    __shared__ float red[4];
    const int o = blockIdx.x;
    const float* wo = w + (size_t)o * 2304;
    const int t = threadIdx.x;
    float v[9];
    float s = 0.f, s2 = 0.f;
#pragma unroll
    for (int i = 0; i < 9; ++i) {
        v[i] = wo[t * 9 + i];
        s += v[i];
        s2 += v[i] * v[i];
    }
    s = block_sum(s, red);
    s2 = block_sum(s2, red);
    const float mu = s * (1.f / 2304.f);
    const float sd = sqrtf(fmaxf(s2 * (1.f / 2304.f) - mu * mu, 0.f));
    float sa = 0.f;
#pragma unroll
    for (int i = 0; i < 9; ++i) sa += fabsf(v[i] - mu);
    sa = block_sum(sa, red);
    if (t == 0) wsc[o] = (sa * (1.f / 2304.f)) / (sd + 1e-5f);
    const int c = t, c32 = c >> 5, hf = (c >> 4) & 1, j = c & 15;
    const int lane = (hf << 5) | (o & 31), octile = o >> 5;
#pragma unroll
    for (int tap = 0; tap < 9; ++tap) {
        const float d = v[tap] - mu;
        const signed char sg = (d > 0.f) ? 1 : ((d < 0.f) ? -1 : 0);
        wf[(size_t)(((tap * 8 + c32) * 8 + octile) * 64 + lane) * 16 + j] = sg;
    }
}

// ---- epilogue params: ep = [f1(256), beta1(256), f2(256), beta2(256)] ----
__global__ void k_prep(const float* __restrict__ g1, const float* __restrict__ b1,
                       const float* __restrict__ m1, const float* __restrict__ v1,
                       const float* __restrict__ g2, const float* __restrict__ b2,
                       const float* __restrict__ m2, const float* __restrict__ v2,
                       const float* __restrict__ a1p, const float* __restrict__ a2p,
                       const float* __restrict__ ws1, const float* __restrict__ ws2,
                       float* __restrict__ ep) {
    const int i = threadIdx.x;
    const float i1 = g1[i] / sqrtf(v1[i] + 1e-5f);
    const float i2 = g2[i] / sqrtf(v2[i] + 1e-5f);
    ep[i] = a1p[0] * ws1[i] * i1;
    ep[256 + i] = b1[i] - m1[i] * i1;
    ep[512 + i] = a2p[0] * ws2[i] * i2;
    ep[768 + i] = b2[i] - m2[i] * i2;
}

// ---- LSQ 4-bit quantize NCHW fp32 -> nibble-packed NHWC ----
// global layout per (n,h,w): 128B = 16 groups x 8B; group g8 byte k = q[g8*16+k] | q[g8*16+k+8]<<4
__global__ __launch_bounds__(256) void k_quant_nhwc(const float* __restrict__ x,
                                                    unsigned char* __restrict__ xq,
                                                    const float* __restrict__ ap) {
    __shared__ unsigned char q[3584];  // [w 56][c 64], dword-swizzled
    const int bid = blockIdx.x;
    const int cg = bid & 3;
    const int h = (bid >> 2) % Hh;
    const int n = bid / (4 * Hh);
    const float a = ap[0];
    const int c0 = cg * 64;
    for (int i = threadIdx.x; i < 3584; i += 256) {
        const int cl = i / 56;
        const int w = i - cl * 56;
        const float v = x[(((size_t)n * Cc + c0 + cl) * Hh + h) * Ww + w];
        const float xs = fminf(fmaxf(v / a, 0.f), 15.f);
        q[w * 64 + (((cl >> 2) ^ (w & 15)) << 2) + (cl & 3)] = (unsigned char)(int)rintf(xs);
    }
    __syncthreads();
    const unsigned int* q32 = (const unsigned int*)q;
    unsigned int* dst = (unsigned int*)xq + ((size_t)(n * Hh + h) * Ww) * 32;
    for (int j = threadIdx.x; j < 448; j += 256) {
        const int w = j >> 3, g8l = (j >> 1) & 3, hf = j & 1;
        const unsigned int lo = q32[w * 16 + ((g8l * 4 + hf) ^ (w & 15))];
        const unsigned int hi = q32[w * 16 + ((g8l * 4 + 2 + hf) ^ (w & 15))];
        dst[w * 32 + (cg * 4 + g8l) * 2 + hf] = lo | (hi << 4);
    }
}

__device__ __forceinline__ v4i unp(u64 p) {
    const unsigned int lo = (unsigned int)p, hi = (unsigned int)(p >> 32);
    v4i b;
    b[0] = (int)(lo & 0x0F0F0F0Fu);
    b[1] = (int)(hi & 0x0F0F0F0Fu);
    b[2] = (int)((lo >> 4) & 0x0F0F0F0Fu);
    b[3] = (int)((hi >> 4) & 0x0F0F0F0Fu);
    return b;
}

// ---- implicit-GEMM conv, i8 MFMA 32x32x32, 4 output rows per block ----
// block: 4 waves x 64 threads; wave g: oc [g*64, g*64+64) x 4 rows x 64 cols
// acc[oct 2][row 4][ct 2] = 256 VGPRs -> 1 wave/SIMD
template <bool QOUT>
__global__ __launch_bounds__(256, 1) void k_conv(const unsigned char* __restrict__ xin,
                                                 const signed char* __restrict__ wf,
                                                 const float* __restrict__ ep,
                                                 const float* __restrict__ a2p,
                                                 unsigned char* __restrict__ hq,
                                                 float* __restrict__ yout) {
    __shared__ unsigned char sm[ACT_LDS];  // acts; hbuf aliased after compute
    const int bid = blockIdx.x;
    const int n = bid / 14;
    const int h0 = (bid % 14) * 4;
    const int tid = threadIdx.x;

    // ---- stage 6 act rows (nibble-packed) -> LDS [row][col 0..57][128B], pad stride 136 ----
    for (int u = tid; u < 6 * 58 * 16; u += 256) {
        const int r = u / 928;
        const int rem = u - r * 928;
        const int col = rem >> 4;
        const int t8 = rem & 15;
        const int y = h0 - 1 + r;
        const int xi = col - 1;
        u64 v = 0;
        if ((unsigned)y < 56u && (unsigned)xi < 56u)
            v = *(const u64*)(xin + ((((size_t)n * Hh + y) * Ww + xi) << 7) + (t8 << 3));
        *(u64*)(sm + r * RSTR + col * CSTR + (t8 << 3)) = v;
    }
    __syncthreads();

    const int lane = tid & 63;
    const int g = tid >> 6;
    const int half = lane >> 5;
    const int lm = lane & 31;

    int cofs[3][2];
#pragma unroll
    for (int kw = 0; kw < 3; ++kw)
#pragma unroll
        for (int ct = 0; ct < 2; ++ct) {
            int col = ct * 32 + lm + kw;
            col = col > 57 ? 57 : col;  // clamp into pad col (w>=56 is dead)
            cofs[kw][ct] = col * CSTR + half * 8;
        }

    v16i acc[2][4][2] = {};
    const v4i* wpg = (const v4i*)wf + 2 * g * 64 + lane;

#pragma unroll 1
    for (int c32 = 0; c32 < 8; ++c32) {
        const int cadd = c32 * 16;
#pragma unroll
        for (int kw = 0; kw < 3; ++kw) {
            v4i bfr[6][2];
#pragma unroll
            for (int ar = 0; ar < 6; ++ar)
#pragma unroll
                for (int ct = 0; ct < 2; ++ct)
                    bfr[ar][ct] = unp(*(const u64*)(sm + ar * RSTR + cofs[kw][ct] + cadd));
#pragma unroll
            for (int kh = 0; kh < 3; ++kh) {
                const int aidx = (kh * 3 + kw) * 4096 + c32 * 512;
                const v4i A0 = wpg[aidx];
                const v4i A1 = wpg[aidx + 64];
#pragma unroll
                for (int r = 0; r < 4; ++r)
#pragma unroll
                    for (int ct = 0; ct < 2; ++ct) {
                        acc[0][r][ct] = __builtin_amdgcn_mfma_i32_32x32x32_i8(
                            A0, bfr[r + kh][ct], acc[0][r][ct], 0, 0, 0);
                        acc[1][r][ct] = __builtin_amdgcn_mfma_i32_32x32x32_i8(
                            A1, bfr[r + kh][ct], acc[1][r][ct], 0, 0, 0);
                    }
            }
        }
    }

    // ---- epilogue ----
    if constexpr (QOUT) {
        __syncthreads();  // acts dead; reuse sm as hbuf [4 rows][56 w][32 dwords]
        unsigned int* hb = (unsigned int*)sm;
        const float inva = 1.0f / a2p[0];
#pragma unroll
        for (int oct = 0; oct < 2; ++oct) {
            const int ocb = g * 64 + oct * 32;
            const int dw0 = (ocb >> 4) * 2 + half;
#pragma unroll
            for (int r = 0; r < 4; ++r)
#pragma unroll
                for (int ct = 0; ct < 2; ++ct) {
                    const int w = ct * 32 + lm;
                    if (w < 56) {
                        const v16i av = acc[oct][r][ct];
                        unsigned int pk0 = 0, pk1 = 0;
#pragma unroll
                        for (int q = 0; q < 4; ++q) {
                            const int oc = ocb + q + 4 * half;
                            unsigned int c0 = (unsigned int)(int)rintf(
                                fminf(fmaxf(fmaf((float)av[q], ep[oc], ep[256 + oc]), 0.f) * inva, 15.f));
                            unsigned int c1 = (unsigned int)(int)rintf(
                                fminf(fmaxf(fmaf((float)av[4 + q], ep[oc + 8], ep[264 + oc]), 0.f) * inva, 15.f));
                            unsigned int c2 = (unsigned int)(int)rintf(
                                fminf(fmaxf(fmaf((float)av[8 + q], ep[oc + 16], ep[272 + oc]), 0.f) * inva, 15.f));
                            unsigned int c3 = (unsigned int)(int)rintf(
                                fminf(fmaxf(fmaf((float)av[12 + q], ep[oc + 24], ep[280 + oc]), 0.f) * inva, 15.f));
                            pk0 |= (c0 | (c1 << 4)) << (8 * q);
                            pk1 |= (c2 | (c3 << 4)) << (8 * q);
                        }
                        const int rowbase = (r * 56 + w) * 32;
                        hb[rowbase + ((dw0) ^ (w & 31))] = pk0;
                        hb[rowbase + ((dw0 + 2) ^ (w & 31))] = pk1;
                    }
                }
        }
        __syncthreads();
        unsigned int* dst = (unsigned int*)hq + ((size_t)(n * Hh + h0) * Ww) * 32;
        for (int j = tid; j < 7168; j += 256) {
            const int rw = j >> 5;          // r*56 + w
            const int w = rw % 56;
            const int d = j & 31;
            dst[j] = hb[(rw << 5) + (d ^ (w & 31))];
        }
    } else {
        float* dst = yout + (size_t)n * Cc * 3136 + (size_t)h0 * 56;
#pragma unroll
        for (int oct = 0; oct < 2; ++oct)
#pragma unroll
            for (int r = 0; r < 4; ++r)
#pragma unroll
                for (int ct = 0; ct < 2; ++ct) {
                    const int w = ct * 32 + lm;
                    if (w < 56) {
                        const v16i av = acc[oct][r][ct];
#pragma unroll
                        for (int reg = 0; reg < 16; ++reg) {
                            const int oc = g * 64 + oct * 32 + (reg & 3) + 8 * (reg >> 2) + 4 * half;
                            dst[(size_t)oc * 3136 + r * 56 + w] =
                                fmaxf(fmaf((float)av[reg], ep[oc], ep[256 + oc]), 0.f);
                        }
                    }
                }
    }
}

extern "C" void kernel_launch(void* const* d_in, const int* in_sizes, int n_in,
                              void* d_out, int out_size, void* d_ws, size_t ws_size,
                              hipStream_t stream) {
    const float* x = (const float*)d_in[0];
    const float* w1 = (const float*)d_in[1];
    const float* a1 = (const float*)d_in[2];
    const float* g1 = (const float*)d_in[3];
    const float* b1 = (const float*)d_in[4];
    const float* m1 = (const float*)d_in[5];
    const float* v1 = (const float*)d_in[6];
    const float* w2 = (const float*)d_in[7];
    const float* a2 = (const float*)d_in[8];
    const float* g2 = (const float*)d_in[9];
    const float* b2 = (const float*)d_in[10];
    const float* m2 = (const float*)d_in[11];
    const float* v2 = (const float*)d_in[12];

    // workspace (~27.1 MB)
    signed char* wf1 = (signed char*)d_ws;             // 589824 B
    signed char* wf2 = wf1 + 589824;                   // 589824 B
    float* wsc1 = (float*)(wf2 + 589824);              // 256 f
    float* wsc2 = wsc1 + 256;                          // 256 f
    float* ep = wsc2 + 256;                            // 1024 f
    unsigned char* xq1 = (unsigned char*)(ep + 1024);  // 12845056 B (packed NHWC)
    unsigned char* hq = xq1 + (size_t)12845056;        // 12845056 B (packed NHWC)

    k_binpack<<<256, 256, 0, stream>>>(w1, wf1, wsc1);
    k_binpack<<<256, 256, 0, stream>>>(w2, wf2, wsc2);
    k_prep<<<1, 256, 0, stream>>>(g1, b1, m1, v1, g2, b2, m2, v2, a1, a2, wsc1, wsc2, ep);
    k_quant_nhwc<<<Bn * Hh * 4, 256, 0, stream>>>(x, xq1, a1);

    // layer 1: packed x -> packed h (BN+ReLU+LSQ(alpha2) fused)
    k_conv<true><<<Bn * 14, 256, 0, stream>>>(xq1, wf1, ep, a2, hq, nullptr);
    // layer 2: packed h -> fp32 NCHW out (BN+ReLU)
    k_conv<false><<<Bn * 14, 256, 0, stream>>>(hq, wf2, ep + 512, nullptr, nullptr, (float*)d_out);
}

// Round 4
// 208.800 us; speedup vs baseline: 17.8410x; 1.1740x over previous
//
#include <hip/hip_runtime.h>
#include <math.h>

typedef int v4i __attribute__((ext_vector_type(4)));
typedef int v16i __attribute__((ext_vector_type(16)));
typedef unsigned long long u64;

#define Bn 32
#define Cc 256
#define Hh 56
#define Ww 56
#define CSTR 136             // LDS bytes per act col (128 packed + 8 pad)
#define RSTR (34 * CSTR)     // 4624 per act row (34 cols: 32 m + 2 halo)
#define ACT_LDS (9 * RSTR)   // 41616

// ---------------- block-wide sum over 256 threads ----------------
__device__ __forceinline__ float block_sum(float v, float* red) {
#pragma unroll
    for (int off = 32; off > 0; off >>= 1) v += __shfl_down(v, off, 64);
    const int wv = threadIdx.x >> 6;
    __syncthreads();
    if ((threadIdx.x & 63) == 0) red[wv] = v;
    __syncthreads();
    return red[0] + red[1] + red[2] + red[3];
}

// ---- IR-Net binarize + pack sign codes into MFMA-fragment-contiguous layout ----
// v4i unit index: ((tap*8 + c32)*8 + octile)*64 + lane ; lane=(half<<5)|(oc&31)
__global__ __launch_bounds__(256) void k_binpack(const float* __restrict__ w,
                                                 signed char* __restrict__ wf,
                                                 float* __restrict__ wsc) {
    __shared__ float red[4];
    const int o = blockIdx.x;
    const float* wo = w + (size_t)o * 2304;
    const int t = threadIdx.x;
    float v[9];
    float s = 0.f, s2 = 0.f;
#pragma unroll
    for (int i = 0; i < 9; ++i) {
        v[i] = wo[t * 9 + i];
        s += v[i];
        s2 += v[i] * v[i];
    }
    s = block_sum(s, red);
    s2 = block_sum(s2, red);
    const float mu = s * (1.f / 2304.f);
    const float sd = sqrtf(fmaxf(s2 * (1.f / 2304.f) - mu * mu, 0.f));
    float sa = 0.f;
#pragma unroll
    for (int i = 0; i < 9; ++i) sa += fabsf(v[i] - mu);
    sa = block_sum(sa, red);
    if (t == 0) wsc[o] = (sa * (1.f / 2304.f)) / (sd + 1e-5f);
    const int c = t, c32 = c >> 5, hf = (c >> 4) & 1, j = c & 15;
    const int lane = (hf << 5) | (o & 31), octile = o >> 5;
#pragma unroll
    for (int tap = 0; tap < 9; ++tap) {
        const float d = v[tap] - mu;
        const signed char sg = (d > 0.f) ? 1 : ((d < 0.f) ? -1 : 0);
        wf[(size_t)(((tap * 8 + c32) * 8 + octile) * 64 + lane) * 16 + j] = sg;
    }
}

// ---- epilogue params: ep = [f1(256), beta1(256), f2(256), beta2(256)] ----
__global__ void k_prep(const float* __restrict__ g1, const float* __restrict__ b1,
                       const float* __restrict__ m1, const float* __restrict__ v1,
                       const float* __restrict__ g2, const float* __restrict__ b2,
                       const float* __restrict__ m2, const float* __restrict__ v2,
                       const float* __restrict__ a1p, const float* __restrict__ a2p,
                       const float* __restrict__ ws1, const float* __restrict__ ws2,
                       float* __restrict__ ep) {
    const int i = threadIdx.x;
    const float i1 = g1[i] / sqrtf(v1[i] + 1e-5f);
    const float i2 = g2[i] / sqrtf(v2[i] + 1e-5f);
    ep[i] = a1p[0] * ws1[i] * i1;
    ep[256 + i] = b1[i] - m1[i] * i1;
    ep[512 + i] = a2p[0] * ws2[i] * i2;
    ep[768 + i] = b2[i] - m2[i] * i2;
}

// ---- LSQ 4-bit quantize NCHW fp32 -> nibble-packed NHWC ----
// per (n,h,w): 128B = 16 groups x 8B; group g8 byte k = q[g8*16+k] | q[g8*16+k+8]<<4
__global__ __launch_bounds__(256) void k_quant_nhwc(const float* __restrict__ x,
                                                    unsigned char* __restrict__ xq,
                                                    const float* __restrict__ ap) {
    __shared__ unsigned char q[3584];  // [w 56][c 64], dword-swizzled
    const int bid = blockIdx.x;
    const int cg = bid & 3;
    const int h = (bid >> 2) % Hh;
    const int n = bid / (4 * Hh);
    const float a = ap[0];
    const int c0 = cg * 64;
    for (int i = threadIdx.x; i < 3584; i += 256) {
        const int cl = i / 56;
        const int w = i - cl * 56;
        const float v = x[(((size_t)n * Cc + c0 + cl) * Hh + h) * Ww + w];
        const float xs = fminf(fmaxf(v / a, 0.f), 15.f);
        q[w * 64 + (((cl >> 2) ^ (w & 15)) << 2) + (cl & 3)] = (unsigned char)(int)rintf(xs);
    }
    __syncthreads();
    const unsigned int* q32 = (const unsigned int*)q;
    unsigned int* dst = (unsigned int*)xq + ((size_t)(n * Hh + h) * Ww) * 32;
    for (int j = threadIdx.x; j < 448; j += 256) {
        const int w = j >> 3, g8l = (j >> 1) & 3, hf = j & 1;
        const unsigned int lo = q32[w * 16 + ((g8l * 4 + hf) ^ (w & 15))];
        const unsigned int hi = q32[w * 16 + ((g8l * 4 + 2 + hf) ^ (w & 15))];
        dst[w * 32 + (cg * 4 + g8l) * 2 + hf] = lo | (hi << 4);
    }
}

__device__ __forceinline__ v4i unp(u64 p) {
    const unsigned int lo = (unsigned int)p, hi = (unsigned int)(p >> 32);
    v4i b;
    b[0] = (int)(lo & 0x0F0F0F0Fu);
    b[1] = (int)(hi & 0x0F0F0F0Fu);
    b[2] = (int)((lo >> 4) & 0x0F0F0F0Fu);
    b[3] = (int)((hi >> 4) & 0x0F0F0F0Fu);
    return b;
}

// ---- implicit-GEMM conv, i8 MFMA 32x32x32 ----
// grid 1024 = 32n x 8hb x 2mh x 2oh ; block 256 thr = 4 waves
// wave g: oc [oh*128+g*32, +32) x 7 rows x 32 cols ; acc = 7 x v16i = 112 VGPR
// 2 waves/SIMD, 2 blocks/CU (LDS 40.6KB) -> grid = exactly 2 rounds, no tail
template <bool QOUT>
__global__ __launch_bounds__(256, 2) void k_conv(const unsigned char* __restrict__ xin,
                                                 const signed char* __restrict__ wf,
                                                 const float* __restrict__ ep,
                                                 const float* __restrict__ a2p,
                                                 unsigned char* __restrict__ hq,
                                                 float* __restrict__ yout) {
    __shared__ __align__(16) unsigned char sm[ACT_LDS];  // acts; hbuf aliased later
    const int bid = blockIdx.x;
    const int oh = bid & 1;
    const int mh = (bid >> 1) & 1;
    const int hb = (bid >> 2) & 7;
    const int n = bid >> 5;
    const int h0 = hb * 7;
    const int mbase = mh * 32;
    const int tid = threadIdx.x;

    // ---- stage 9 act rows x 34 cols (nibble-packed) -> LDS ----
    for (int u = tid; u < 9 * 34 * 16; u += 256) {
        const int r = u / 544;
        const int rem = u - r * 544;
        const int col = rem >> 4;
        const int t8 = rem & 15;
        const int y = h0 - 1 + r;
        const int xi = mbase - 1 + col;
        u64 v = 0;
        if ((unsigned)y < 56u && (unsigned)xi < 56u)
            v = *(const u64*)(xin + ((((size_t)n * Hh + y) * Ww + xi) << 7) + (t8 << 3));
        *(u64*)(sm + r * RSTR + col * CSTR + (t8 << 3)) = v;
    }
    __syncthreads();

    const int lane = tid & 63;
    const int g = tid >> 6;
    const int half = lane >> 5;
    const int lm = lane & 31;
    const int octile = oh * 4 + g;

    v16i acc[7] = {};
    const v4i* wpg = (const v4i*)wf + octile * 64 + lane;
    const unsigned char* bp0 = sm + lm * CSTR + half * 8;

#pragma unroll 1
    for (int c32 = 0; c32 < 8; ++c32) {
        v4i aw[9];
#pragma unroll
        for (int tap = 0; tap < 9; ++tap) aw[tap] = wpg[(tap * 8 + c32) << 9];
        const unsigned char* bp = bp0 + c32 * 16;
#pragma unroll
        for (int kw = 0; kw < 3; ++kw) {
            v4i bfr[9];
#pragma unroll
            for (int ar = 0; ar < 9; ++ar)
                bfr[ar] = unp(*(const u64*)(bp + kw * CSTR + ar * RSTR));
#pragma unroll
            for (int kh = 0; kh < 3; ++kh) {
#pragma unroll
                for (int r = 0; r < 7; ++r)
                    acc[r] = __builtin_amdgcn_mfma_i32_32x32x32_i8(aw[kh * 3 + kw],
                                                                   bfr[r + kh], acc[r], 0, 0, 0);
            }
        }
    }

    // ---- epilogue ----
    if constexpr (QOUT) {
        __syncthreads();  // acts dead; reuse sm as hbuf [7 r][32 w][16 dwords]
        unsigned int* hb = (unsigned int*)sm;
        const float inva = 1.0f / a2p[0];
        const int oc0w = oh * 128 + g * 32;
        const int d0 = 4 * g + half;
#pragma unroll
        for (int r = 0; r < 7; ++r) {
            const v16i av = acc[r];
            unsigned int pk0 = 0, pk1 = 0;
#pragma unroll
            for (int q = 0; q < 4; ++q) {
                const int oc = oc0w + 4 * half + q;
                const unsigned int c0 = (unsigned int)(int)rintf(
                    fminf(fmaxf(fmaf((float)av[q], ep[oc], ep[256 + oc]), 0.f) * inva, 15.f));
                const unsigned int c1 = (unsigned int)(int)rintf(
                    fminf(fmaxf(fmaf((float)av[4 + q], ep[oc + 8], ep[264 + oc]), 0.f) * inva, 15.f));
                const unsigned int c2 = (unsigned int)(int)rintf(
                    fminf(fmaxf(fmaf((float)av[8 + q], ep[oc + 16], ep[272 + oc]), 0.f) * inva, 15.f));
                const unsigned int c3 = (unsigned int)(int)rintf(
                    fminf(fmaxf(fmaf((float)av[12 + q], ep[oc + 24], ep[280 + oc]), 0.f) * inva, 15.f));
                pk0 |= (c0 | (c1 << 4)) << (8 * q);
                pk1 |= (c2 | (c3 << 4)) << (8 * q);
            }
            const int rb = (r * 32 + lm) * 16;
            hb[rb + (d0 ^ (lm & 15))] = pk0;
            hb[rb + ((d0 + 2) ^ (lm & 15))] = pk1;
        }
        __syncthreads();
        unsigned int* dst = (unsigned int*)hq;
        for (int j = tid; j < 7 * 32 * 16; j += 256) {
            const int rw = j >> 4, dw = j & 15;
            const int r = rw >> 5, wl = rw & 31;
            const int w = mbase + wl;
            if (w < 56)
                dst[((size_t)((n * Hh + h0 + r) * Ww) + w) * 32 + oh * 16 + dw] =
                    hb[(rw << 4) + (dw ^ (wl & 15))];
        }
    } else {
        const int w = mbase + lm;
        if (w < 56) {
            float* dst = yout + (size_t)n * Cc * 3136 + (size_t)h0 * 56 + w;
#pragma unroll
            for (int r = 0; r < 7; ++r) {
                const v16i av = acc[r];
#pragma unroll
                for (int reg = 0; reg < 16; ++reg) {
                    const int oc = oh * 128 + g * 32 + (reg & 3) + 8 * (reg >> 2) + 4 * half;
                    dst[(size_t)oc * 3136 + r * 56] =
                        fmaxf(fmaf((float)av[reg], ep[oc], ep[256 + oc]), 0.f);
                }
            }
        }
    }
}

extern "C" void kernel_launch(void* const* d_in, const int* in_sizes, int n_in,
                              void* d_out, int out_size, void* d_ws, size_t ws_size,
                              hipStream_t stream) {
    const float* x = (const float*)d_in[0];
    const float* w1 = (const float*)d_in[1];
    const float* a1 = (const float*)d_in[2];
    const float* g1 = (const float*)d_in[3];
    const float* b1 = (const float*)d_in[4];
    const float* m1 = (const float*)d_in[5];
    const float* v1 = (const float*)d_in[6];
    const float* w2 = (const float*)d_in[7];
    const float* a2 = (const float*)d_in[8];
    const float* g2 = (const float*)d_in[9];
    const float* b2 = (const float*)d_in[10];
    const float* m2 = (const float*)d_in[11];
    const float* v2 = (const float*)d_in[12];

    // workspace (~27.1 MB)
    signed char* wf1 = (signed char*)d_ws;             // 589824 B
    signed char* wf2 = wf1 + 589824;                   // 589824 B
    float* wsc1 = (float*)(wf2 + 589824);              // 256 f
    float* wsc2 = wsc1 + 256;                          // 256 f
    float* ep = wsc2 + 256;                            // 1024 f
    unsigned char* xq1 = (unsigned char*)(ep + 1024);  // 12845056 B (packed NHWC)
    unsigned char* hq = xq1 + (size_t)12845056;        // 12845056 B (packed NHWC)

    k_binpack<<<256, 256, 0, stream>>>(w1, wf1, wsc1);
    k_binpack<<<256, 256, 0, stream>>>(w2, wf2, wsc2);
    k_prep<<<1, 256, 0, stream>>>(g1, b1, m1, v1, g2, b2, m2, v2, a1, a2, wsc1, wsc2, ep);
    k_quant_nhwc<<<Bn * Hh * 4, 256, 0, stream>>>(x, xq1, a1);

    // layer 1: packed x -> packed h (BN+ReLU+LSQ(alpha2) fused)
    k_conv<true><<<1024, 256, 0, stream>>>(xq1, wf1, ep, a2, hq, nullptr);
    // layer 2: packed h -> fp32 NCHW out (BN+ReLU)
    k_conv<false><<<1024, 256, 0, stream>>>(hq, wf2, ep + 512, nullptr, nullptr, (float*)d_out);
}

// Round 5
// 194.649 us; speedup vs baseline: 19.1381x; 1.0727x over previous
//
#include <hip/hip_runtime.h>
#include <math.h>

typedef int v4i __attribute__((ext_vector_type(4)));
typedef int v16i __attribute__((ext_vector_type(16)));
typedef unsigned long long u64;

#define Bn 32
#define Cc 256
#define Hh 56
#define Ww 56
#define CSTR 136             // LDS bytes per act col (128 packed + 8 pad)
#define RSTR (34 * CSTR)     // 4624 per act row (34 cols: 32 m + 2 halo)
#define ACT_LDS (9 * RSTR)   // 41616
#define NSTG (9 * 34 * 16)   // 4896 u64 staged per block

// ---------------- block-wide sum over 256 threads ----------------
__device__ __forceinline__ float block_sum(float v, float* red) {
#pragma unroll
    for (int off = 32; off > 0; off >>= 1) v += __shfl_down(v, off, 64);
    const int wv = threadIdx.x >> 6;
    __syncthreads();
    if ((threadIdx.x & 63) == 0) red[wv] = v;
    __syncthreads();
    return red[0] + red[1] + red[2] + red[3];
}

// ---- IR-Net binarize + pack sign codes into MFMA-fragment-contiguous layout ----
// v4i unit index: ((tap*8 + c32)*8 + octile)*64 + lane ; lane=(half<<5)|(oc&31)
__global__ __launch_bounds__(256) void k_binpack(const float* __restrict__ w,
                                                 signed char* __restrict__ wf,
                                                 float* __restrict__ wsc) {
    __shared__ float red[4];
    const int o = blockIdx.x;
    const float* wo = w + (size_t)o * 2304;
    const int t = threadIdx.x;
    float v[9];
    float s = 0.f, s2 = 0.f;
#pragma unroll
    for (int i = 0; i < 9; ++i) {
        v[i] = wo[t * 9 + i];
        s += v[i];
        s2 += v[i] * v[i];
    }
    s = block_sum(s, red);
    s2 = block_sum(s2, red);
    const float mu = s * (1.f / 2304.f);
    const float sd = sqrtf(fmaxf(s2 * (1.f / 2304.f) - mu * mu, 0.f));
    float sa = 0.f;
#pragma unroll
    for (int i = 0; i < 9; ++i) sa += fabsf(v[i] - mu);
    sa = block_sum(sa, red);
    if (t == 0) wsc[o] = (sa * (1.f / 2304.f)) / (sd + 1e-5f);
    const int c = t, c32 = c >> 5, hf = (c >> 4) & 1, j = c & 15;
    const int lane = (hf << 5) | (o & 31), octile = o >> 5;
#pragma unroll
    for (int tap = 0; tap < 9; ++tap) {
        const float d = v[tap] - mu;
        const signed char sg = (d > 0.f) ? 1 : ((d < 0.f) ? -1 : 0);
        wf[(size_t)(((tap * 8 + c32) * 8 + octile) * 64 + lane) * 16 + j] = sg;
    }
}

// ---- epilogue params: ep = [f1(256), beta1(256), f2(256), beta2(256)] ----
__global__ void k_prep(const float* __restrict__ g1, const float* __restrict__ b1,
                       const float* __restrict__ m1, const float* __restrict__ v1,
                       const float* __restrict__ g2, const float* __restrict__ b2,
                       const float* __restrict__ m2, const float* __restrict__ v2,
                       const float* __restrict__ a1p, const float* __restrict__ a2p,
                       const float* __restrict__ ws1, const float* __restrict__ ws2,
                       float* __restrict__ ep) {
    const int i = threadIdx.x;
    const float i1 = g1[i] / sqrtf(v1[i] + 1e-5f);
    const float i2 = g2[i] / sqrtf(v2[i] + 1e-5f);
    ep[i] = a1p[0] * ws1[i] * i1;
    ep[256 + i] = b1[i] - m1[i] * i1;
    ep[512 + i] = a2p[0] * ws2[i] * i2;
    ep[768 + i] = b2[i] - m2[i] * i2;
}

// ---- LSQ 4-bit quantize NCHW fp32 -> nibble-packed NHWC ----
// per (n,h,w): 128B = 16 groups x 8B; group g8 byte k = q[g8*16+k] | q[g8*16+k+8]<<4
__global__ __launch_bounds__(256) void k_quant_nhwc(const float* __restrict__ x,
                                                    unsigned char* __restrict__ xq,
                                                    const float* __restrict__ ap) {
    __shared__ unsigned char q[3584];  // [w 56][c 64], dword-swizzled
    const int bid = blockIdx.x;
    const int cg = bid & 3;
    const int h = (bid >> 2) % Hh;
    const int n = bid / (4 * Hh);
    const float a = ap[0];
    const int c0 = cg * 64;
    for (int i = threadIdx.x; i < 3584; i += 256) {
        const int cl = i / 56;
        const int w = i - cl * 56;
        const float v = x[(((size_t)n * Cc + c0 + cl) * Hh + h) * Ww + w];
        const float xs = fminf(fmaxf(v / a, 0.f), 15.f);
        q[w * 64 + (((cl >> 2) ^ (w & 15)) << 2) + (cl & 3)] = (unsigned char)(int)rintf(xs);
    }
    __syncthreads();
    const unsigned int* q32 = (const unsigned int*)q;
    unsigned int* dst = (unsigned int*)xq + ((size_t)(n * Hh + h) * Ww) * 32;
    for (int j = threadIdx.x; j < 448; j += 256) {
        const int w = j >> 3, g8l = (j >> 1) & 3, hf = j & 1;
        const unsigned int lo = q32[w * 16 + ((g8l * 4 + hf) ^ (w & 15))];
        const unsigned int hi = q32[w * 16 + ((g8l * 4 + 2 + hf) ^ (w & 15))];
        dst[w * 32 + (cg * 4 + g8l) * 2 + hf] = lo | (hi << 4);
    }
}

__device__ __forceinline__ v4i unp(u64 p) {
    const unsigned int lo = (unsigned int)p, hi = (unsigned int)(p >> 32);
    v4i b;
    b[0] = (int)(lo & 0x0F0F0F0Fu);
    b[1] = (int)(hi & 0x0F0F0F0Fu);
    b[2] = (int)((lo >> 4) & 0x0F0F0F0Fu);
    b[3] = (int)((hi >> 4) & 0x0F0F0F0Fu);
    return b;
}

// ---- implicit-GEMM conv, i8 MFMA 32x32x32 ----
// grid 1024 = 32n x 8hb x 2mh x 2oh ; block 256 thr = 4 waves
// wave g: oc [oh*128+g*32, +32) x 7 rows x 32 cols ; acc = 7 x v16i
// 2 waves/SIMD, 2 blocks/CU -> grid = exactly 2 rounds
template <bool QOUT>
__global__ __launch_bounds__(256, 2) void k_conv(const unsigned char* __restrict__ xin,
                                                 const signed char* __restrict__ wf,
                                                 const float* __restrict__ ep,
                                                 const float* __restrict__ a2p,
                                                 unsigned char* __restrict__ hq,
                                                 float* __restrict__ yout) {
    __shared__ __align__(16) unsigned char sm[ACT_LDS];  // acts; hbuf aliased later
    const int bid = blockIdx.x;
    const int oh = bid & 1;
    const int mh = (bid >> 1) & 1;
    const int hb = (bid >> 2) & 7;
    const int n = bid >> 5;
    const int h0 = hb * 7;
    const int mbase = mh * 32;
    const int tid = threadIdx.x;

    // ---- stage 9 act rows x 34 cols (nibble-packed) -> LDS ----
    // two-phase, fully unrolled: 20 independent clamped loads ALL in flight,
    // then predicated zero-select + ds_write (descending-vmcnt drain).
    {
        u64 tmp[20];
#pragma unroll
        for (int k = 0; k < 20; ++k) {
            int u = tid + (k << 8);
            u = u > (NSTG - 1) ? (NSTG - 1) : u;
            const int r = u / 544;
            const int rem = u - r * 544;
            const int col = rem >> 4;
            const int t8 = rem & 15;
            int y = h0 - 1 + r;
            int xi = mbase - 1 + col;
            y = y < 0 ? 0 : (y > 55 ? 55 : y);
            xi = xi < 0 ? 0 : (xi > 55 ? 55 : xi);
            tmp[k] = *(const u64*)(xin + ((((size_t)n * Hh + y) * Ww + xi) << 7) + (t8 << 3));
        }
#pragma unroll
        for (int k = 0; k < 20; ++k) {
            const int u = tid + (k << 8);
            if (u < NSTG) {
                const int r = u / 544;
                const int rem = u - r * 544;
                const int col = rem >> 4;
                const int y = h0 - 1 + r;
                const int xi = mbase - 1 + col;
                const u64 v = ((unsigned)y < 56u && (unsigned)xi < 56u) ? tmp[k] : 0;
                *(u64*)(sm + r * RSTR + col * CSTR + ((rem & 15) << 3)) = v;
            }
        }
    }
    __syncthreads();

    const int lane = tid & 63;
    const int g = tid >> 6;
    const int half = lane >> 5;
    const int lm = lane & 31;
    const int octile = oh * 4 + g;

    v16i acc[7] = {};
    const v4i* wpg = (const v4i*)wf + octile * 64 + lane;
    const unsigned char* bp0 = sm + lm * CSTR + half * 8;

#pragma unroll 1
    for (int c32 = 0; c32 < 8; ++c32) {
        v4i aw[9];
#pragma unroll
        for (int tap = 0; tap < 9; ++tap) aw[tap] = wpg[(tap * 8 + c32) << 9];
        const unsigned char* bp = bp0 + c32 * 16;
#pragma unroll
        for (int kw = 0; kw < 3; ++kw) {
            v4i bfr[9];
#pragma unroll
            for (int ar = 0; ar < 9; ++ar)
                bfr[ar] = unp(*(const u64*)(bp + kw * CSTR + ar * RSTR));
#pragma unroll
            for (int kh = 0; kh < 3; ++kh) {
#pragma unroll
                for (int r = 0; r < 7; ++r)
                    acc[r] = __builtin_amdgcn_mfma_i32_32x32x32_i8(aw[kh * 3 + kw],
                                                                   bfr[r + kh], acc[r], 0, 0, 0);
            }
        }
    }

    // ---- epilogue ----
    if constexpr (QOUT) {
        __syncthreads();  // acts dead; reuse sm as hbuf [7 r][32 w][16 dwords]
        unsigned int* hb = (unsigned int*)sm;
        const float inva = 1.0f / a2p[0];
        const int oc0w = oh * 128 + g * 32;
        const int d0 = 4 * g + half;
#pragma unroll
        for (int r = 0; r < 7; ++r) {
            const v16i av = acc[r];
            unsigned int pk0 = 0, pk1 = 0;
#pragma unroll
            for (int q = 0; q < 4; ++q) {
                const int oc = oc0w + 4 * half + q;
                const unsigned int c0 = (unsigned int)(int)rintf(
                    fminf(fmaxf(fmaf((float)av[q], ep[oc], ep[256 + oc]), 0.f) * inva, 15.f));
                const unsigned int c1 = (unsigned int)(int)rintf(
                    fminf(fmaxf(fmaf((float)av[4 + q], ep[oc + 8], ep[264 + oc]), 0.f) * inva, 15.f));
                const unsigned int c2 = (unsigned int)(int)rintf(
                    fminf(fmaxf(fmaf((float)av[8 + q], ep[oc + 16], ep[272 + oc]), 0.f) * inva, 15.f));
                const unsigned int c3 = (unsigned int)(int)rintf(
                    fminf(fmaxf(fmaf((float)av[12 + q], ep[oc + 24], ep[280 + oc]), 0.f) * inva, 15.f));
                pk0 |= (c0 | (c1 << 4)) << (8 * q);
                pk1 |= (c2 | (c3 << 4)) << (8 * q);
            }
            const int rb = (r * 32 + lm) * 16;
            hb[rb + (d0 ^ (lm & 15))] = pk0;
            hb[rb + ((d0 + 2) ^ (lm & 15))] = pk1;
        }
        __syncthreads();
        unsigned int* dst = (unsigned int*)hq;
        for (int j = tid; j < 7 * 32 * 16; j += 256) {
            const int rw = j >> 4, dw = j & 15;
            const int r = rw >> 5, wl = rw & 31;
            const int w = mbase + wl;
            if (w < 56)
                dst[((size_t)((n * Hh + h0 + r) * Ww) + w) * 32 + oh * 16 + dw] =
                    hb[(rw << 4) + (dw ^ (wl & 15))];
        }
    } else {
        const int w = mbase + lm;
        if (w < 56) {
            float* dst = yout + (size_t)n * Cc * 3136 + (size_t)h0 * 56 + w;
#pragma unroll
            for (int r = 0; r < 7; ++r) {
                const v16i av = acc[r];
#pragma unroll
                for (int reg = 0; reg < 16; ++reg) {
                    const int oc = oh * 128 + g * 32 + (reg & 3) + 8 * (reg >> 2) + 4 * half;
                    dst[(size_t)oc * 3136 + r * 56] =
                        fmaxf(fmaf((float)av[reg], ep[oc], ep[256 + oc]), 0.f);
                }
            }
        }
    }
}

extern "C" void kernel_launch(void* const* d_in, const int* in_sizes, int n_in,
                              void* d_out, int out_size, void* d_ws, size_t ws_size,
                              hipStream_t stream) {
    const float* x = (const float*)d_in[0];
    const float* w1 = (const float*)d_in[1];
    const float* a1 = (const float*)d_in[2];
    const float* g1 = (const float*)d_in[3];
    const float* b1 = (const float*)d_in[4];
    const float* m1 = (const float*)d_in[5];
    const float* v1 = (const float*)d_in[6];
    const float* w2 = (const float*)d_in[7];
    const float* a2 = (const float*)d_in[8];
    const float* g2 = (const float*)d_in[9];
    const float* b2 = (const float*)d_in[10];
    const float* m2 = (const float*)d_in[11];
    const float* v2 = (const float*)d_in[12];

    // workspace (~27.1 MB)
    signed char* wf1 = (signed char*)d_ws;             // 589824 B
    signed char* wf2 = wf1 + 589824;                   // 589824 B
    float* wsc1 = (float*)(wf2 + 589824);              // 256 f
    float* wsc2 = wsc1 + 256;                          // 256 f
    float* ep = wsc2 + 256;                            // 1024 f
    unsigned char* xq1 = (unsigned char*)(ep + 1024);  // 12845056 B (packed NHWC)
    unsigned char* hq = xq1 + (size_t)12845056;        // 12845056 B (packed NHWC)

    k_binpack<<<256, 256, 0, stream>>>(w1, wf1, wsc1);
    k_binpack<<<256, 256, 0, stream>>>(w2, wf2, wsc2);
    k_prep<<<1, 256, 0, stream>>>(g1, b1, m1, v1, g2, b2, m2, v2, a1, a2, wsc1, wsc2, ep);
    k_quant_nhwc<<<Bn * Hh * 4, 256, 0, stream>>>(x, xq1, a1);

    // layer 1: packed x -> packed h (BN+ReLU+LSQ(alpha2) fused)
    k_conv<true><<<1024, 256, 0, stream>>>(xq1, wf1, ep, a2, hq, nullptr);
    // layer 2: packed h -> fp32 NCHW out (BN+ReLU)
    k_conv<false><<<1024, 256, 0, stream>>>(hq, wf2, ep + 512, nullptr, nullptr, (float*)d_out);
}

// Round 6
// 179.920 us; speedup vs baseline: 20.7048x; 1.0819x over previous
//
#include <hip/hip_runtime.h>
#include <math.h>

typedef int v4i __attribute__((ext_vector_type(4)));
typedef int v16i __attribute__((ext_vector_type(16)));
typedef unsigned long long u64;

#define Bn 32
#define Cc 256
#define Hh 56
#define Ww 56
#define RSTR (34 * 256)      // LDS bytes per act row: 34 cols x 256 u8 channels
#define ACT_LDS (9 * RSTR)   // 78336 ; x2 blocks = 156672 <= 160 KiB
#define NSTG (9 * 34 * 16)   // 4896 packed u64 staged per block

// ---------------- block-wide sum over 256 threads ----------------
__device__ __forceinline__ float block_sum(float v, float* red) {
#pragma unroll
    for (int off = 32; off > 0; off >>= 1) v += __shfl_down(v, off, 64);
    const int wv = threadIdx.x >> 6;
    __syncthreads();
    if ((threadIdx.x & 63) == 0) red[wv] = v;
    __syncthreads();
    return red[0] + red[1] + red[2] + red[3];
}

// ---- IR-Net binarize + pack sign codes into MFMA-fragment-contiguous layout ----
// v4i unit index: ((tap*8 + c32)*8 + octile)*64 + lane ; lane=(half<<5)|(oc&31)
__global__ __launch_bounds__(256) void k_binpack(const float* __restrict__ w,
                                                 signed char* __restrict__ wf,
                                                 float* __restrict__ wsc) {
    __shared__ float red[4];
    const int o = blockIdx.x;
    const float* wo = w + (size_t)o * 2304;
    const int t = threadIdx.x;
    float v[9];
    float s = 0.f, s2 = 0.f;
#pragma unroll
    for (int i = 0; i < 9; ++i) {
        v[i] = wo[t * 9 + i];
        s += v[i];
        s2 += v[i] * v[i];
    }
    s = block_sum(s, red);
    s2 = block_sum(s2, red);
    const float mu = s * (1.f / 2304.f);
    const float sd = sqrtf(fmaxf(s2 * (1.f / 2304.f) - mu * mu, 0.f));
    float sa = 0.f;
#pragma unroll
    for (int i = 0; i < 9; ++i) sa += fabsf(v[i] - mu);
    sa = block_sum(sa, red);
    if (t == 0) wsc[o] = (sa * (1.f / 2304.f)) / (sd + 1e-5f);
    const int c = t, c32 = c >> 5, hf = (c >> 4) & 1, j = c & 15;
    const int lane = (hf << 5) | (o & 31), octile = o >> 5;
#pragma unroll
    for (int tap = 0; tap < 9; ++tap) {
        const float d = v[tap] - mu;
        const signed char sg = (d > 0.f) ? 1 : ((d < 0.f) ? -1 : 0);
        wf[(size_t)(((tap * 8 + c32) * 8 + octile) * 64 + lane) * 16 + j] = sg;
    }
}

// ---- epilogue params: ep = [f1(256), beta1(256), f2(256), beta2(256)] ----
__global__ void k_prep(const float* __restrict__ g1, const float* __restrict__ b1,
                       const float* __restrict__ m1, const float* __restrict__ v1,
                       const float* __restrict__ g2, const float* __restrict__ b2,
                       const float* __restrict__ m2, const float* __restrict__ v2,
                       const float* __restrict__ a1p, const float* __restrict__ a2p,
                       const float* __restrict__ ws1, const float* __restrict__ ws2,
                       float* __restrict__ ep) {
    const int i = threadIdx.x;
    const float i1 = g1[i] / sqrtf(v1[i] + 1e-5f);
    const float i2 = g2[i] / sqrtf(v2[i] + 1e-5f);
    ep[i] = a1p[0] * ws1[i] * i1;
    ep[256 + i] = b1[i] - m1[i] * i1;
    ep[512 + i] = a2p[0] * ws2[i] * i2;
    ep[768 + i] = b2[i] - m2[i] * i2;
}

// ---- LSQ 4-bit quantize NCHW fp32 -> nibble-packed NHWC ----
// per (n,h,w): 128B = 16 groups x 8B; group g8 byte k = q[g8*16+k] | q[g8*16+k+8]<<4
__global__ __launch_bounds__(256) void k_quant_nhwc(const float* __restrict__ x,
                                                    unsigned char* __restrict__ xq,
                                                    const float* __restrict__ ap) {
    __shared__ unsigned char q[3584];  // [w 56][c 64], dword-swizzled
    const int bid = blockIdx.x;
    const int cg = bid & 3;
    const int h = (bid >> 2) % Hh;
    const int n = bid / (4 * Hh);
    const float a = ap[0];
    const int c0 = cg * 64;
    for (int i = threadIdx.x; i < 3584; i += 256) {
        const int cl = i / 56;
        const int w = i - cl * 56;
        const float v = x[(((size_t)n * Cc + c0 + cl) * Hh + h) * Ww + w];
        const float xs = fminf(fmaxf(v / a, 0.f), 15.f);
        q[w * 64 + (((cl >> 2) ^ (w & 15)) << 2) + (cl & 3)] = (unsigned char)(int)rintf(xs);
    }
    __syncthreads();
    const unsigned int* q32 = (const unsigned int*)q;
    unsigned int* dst = (unsigned int*)xq + ((size_t)(n * Hh + h) * Ww) * 32;
    for (int j = threadIdx.x; j < 448; j += 256) {
        const int w = j >> 3, g8l = (j >> 1) & 3, hf = j & 1;
        const unsigned int lo = q32[w * 16 + ((g8l * 4 + hf) ^ (w & 15))];
        const unsigned int hi = q32[w * 16 + ((g8l * 4 + 2 + hf) ^ (w & 15))];
        dst[w * 32 + (cg * 4 + g8l) * 2 + hf] = lo | (hi << 4);
    }
}

// ---- implicit-GEMM conv, i8 MFMA 32x32x32 ----
// grid 1024 = 32n x 8hb x 2mh x 2oh ; block 256 thr = 4 waves
// wave g: oc [oh*128+g*32, +32) x 7 rows x 32 cols ; acc = 7 x v16i
// LDS acts UNPACKED u8 (XOR-swizzled 16B groups) -> ds_read_b128 feeds MFMA
// directly, no unpack VALU between read and MFMA.
template <bool QOUT>
__global__ __launch_bounds__(256, 2) void k_conv(const unsigned char* __restrict__ xin,
                                                 const signed char* __restrict__ wf,
                                                 const float* __restrict__ ep,
                                                 const float* __restrict__ a2p,
                                                 unsigned char* __restrict__ hq,
                                                 float* __restrict__ yout) {
    __shared__ __align__(16) unsigned char sm[ACT_LDS];  // acts; hbuf aliased later
    const int bid = blockIdx.x;
    const int oh = bid & 1;
    const int mh = (bid >> 1) & 1;
    const int hb = (bid >> 2) & 7;
    const int n = bid >> 5;
    const int h0 = hb * 7;
    const int mbase = mh * 32;
    const int tid = threadIdx.x;

    // ---- stage 9 act rows x 34 cols: packed global -> UNPACKED u8 LDS ----
    // layout: sm[r*RSTR + col*256 + ((t8 ^ (col&15))<<4)] = 16 channels t8*16..+15
    {
        u64 tmp[20];
#pragma unroll
        for (int k = 0; k < 20; ++k) {
            int u = tid + (k << 8);
            u = u > (NSTG - 1) ? (NSTG - 1) : u;
            const int r = u / 544;
            const int rem = u - r * 544;
            const int col = rem >> 4;
            const int t8 = rem & 15;
            int y = h0 - 1 + r;
            int xi = mbase - 1 + col;
            y = y < 0 ? 0 : (y > 55 ? 55 : y);
            xi = xi < 0 ? 0 : (xi > 55 ? 55 : xi);
            tmp[k] = *(const u64*)(xin + ((((size_t)n * Hh + y) * Ww + xi) << 7) + (t8 << 3));
        }
#pragma unroll
        for (int k = 0; k < 20; ++k) {
            const int u = tid + (k << 8);
            if (u < NSTG) {
                const int r = u / 544;
                const int rem = u - r * 544;
                const int col = rem >> 4;
                const int t8 = rem & 15;
                const int y = h0 - 1 + r;
                const int xi = mbase - 1 + col;
                const u64 p = ((unsigned)y < 56u && (unsigned)xi < 56u) ? tmp[k] : 0;
                const u64 lo = p & 0x0F0F0F0F0F0F0F0FULL;
                const u64 hi = (p >> 4) & 0x0F0F0F0F0F0F0F0FULL;
                v4i wv;
                wv[0] = (int)lo;
                wv[1] = (int)(lo >> 32);
                wv[2] = (int)hi;
                wv[3] = (int)(hi >> 32);
                *(v4i*)(sm + r * RSTR + col * 256 + ((t8 ^ (col & 15)) << 4)) = wv;
            }
        }
    }
    __syncthreads();

    const int lane = tid & 63;
    const int g = tid >> 6;
    const int half = lane >> 5;
    const int lm = lane & 31;
    const int octile = oh * 4 + g;

    v16i acc[7] = {};
    const v4i* wpg = (const v4i*)wf + octile * 64 + lane;

    // per-kw swizzle base: addr(kw,c32,ar) = pkw[kw] ^ (c32<<5)  + ar*RSTR
    // (t8 = c32*2+half; t8<<4 = (c32<<5)|(half<<4); XOR with (col&15)<<4)
    int pkw[3];
#pragma unroll
    for (int kw = 0; kw < 3; ++kw) {
        const int col = lm + kw;  // 0..33, in range, no clamp needed
        pkw[kw] = (col * 256) ^ (half << 4) ^ ((col & 15) << 4);
    }

#pragma unroll 1
    for (int c32 = 0; c32 < 8; ++c32) {
        v4i aw[9];
#pragma unroll
        for (int tap = 0; tap < 9; ++tap) aw[tap] = wpg[(tap * 8 + c32) << 9];
        const int cs = c32 << 5;
#pragma unroll
        for (int kw = 0; kw < 3; ++kw) {
            const unsigned char* bp = sm + (pkw[kw] ^ cs);
            v4i bfr[9];
#pragma unroll
            for (int ar = 0; ar < 9; ++ar)
                bfr[ar] = *(const v4i*)(bp + ar * RSTR);
#pragma unroll
            for (int kh = 0; kh < 3; ++kh) {
#pragma unroll
                for (int r = 0; r < 7; ++r)
                    acc[r] = __builtin_amdgcn_mfma_i32_32x32x32_i8(aw[kh * 3 + kw],
                                                                   bfr[r + kh], acc[r], 0, 0, 0);
            }
        }
    }

    // ---- epilogue ----
    if constexpr (QOUT) {
        __syncthreads();  // acts dead; reuse sm as hbuf [7 r][32 w][16 dwords]
        unsigned int* hb = (unsigned int*)sm;
        const float inva = 1.0f / a2p[0];
        const int oc0w = oh * 128 + g * 32;
        const int d0 = 4 * g + half;
#pragma unroll
        for (int r = 0; r < 7; ++r) {
            const v16i av = acc[r];
            unsigned int pk0 = 0, pk1 = 0;
#pragma unroll
            for (int q = 0; q < 4; ++q) {
                const int oc = oc0w + 4 * half + q;
                const unsigned int c0 = (unsigned int)(int)rintf(
                    fminf(fmaxf(fmaf((float)av[q], ep[oc], ep[256 + oc]), 0.f) * inva, 15.f));
                const unsigned int c1 = (unsigned int)(int)rintf(
                    fminf(fmaxf(fmaf((float)av[4 + q], ep[oc + 8], ep[264 + oc]), 0.f) * inva, 15.f));
                const unsigned int c2 = (unsigned int)(int)rintf(
                    fminf(fmaxf(fmaf((float)av[8 + q], ep[oc + 16], ep[272 + oc]), 0.f) * inva, 15.f));
                const unsigned int c3 = (unsigned int)(int)rintf(
                    fminf(fmaxf(fmaf((float)av[12 + q], ep[oc + 24], ep[280 + oc]), 0.f) * inva, 15.f));
                pk0 |= (c0 | (c1 << 4)) << (8 * q);
                pk1 |= (c2 | (c3 << 4)) << (8 * q);
            }
            const int rb = (r * 32 + lm) * 16;
            hb[rb + (d0 ^ (lm & 15))] = pk0;
            hb[rb + ((d0 + 2) ^ (lm & 15))] = pk1;
        }
        __syncthreads();
        unsigned int* dst = (unsigned int*)hq;
        for (int j = tid; j < 7 * 32 * 16; j += 256) {
            const int rw = j >> 4, dw = j & 15;
            const int r = rw >> 5, wl = rw & 31;
            const int w = mbase + wl;
            if (w < 56)
                dst[((size_t)((n * Hh + h0 + r) * Ww) + w) * 32 + oh * 16 + dw] =
                    hb[(rw << 4) + (dw ^ (wl & 15))];
        }
    } else {
        const int w = mbase + lm;
        if (w < 56) {
            float* dst = yout + (size_t)n * Cc * 3136 + (size_t)h0 * 56 + w;
#pragma unroll
            for (int r = 0; r < 7; ++r) {
                const v16i av = acc[r];
#pragma unroll
                for (int reg = 0; reg < 16; ++reg) {
                    const int oc = oh * 128 + g * 32 + (reg & 3) + 8 * (reg >> 2) + 4 * half;
                    dst[(size_t)oc * 3136 + r * 56] =
                        fmaxf(fmaf((float)av[reg], ep[oc], ep[256 + oc]), 0.f);
                }
            }
        }
    }
}

extern "C" void kernel_launch(void* const* d_in, const int* in_sizes, int n_in,
                              void* d_out, int out_size, void* d_ws, size_t ws_size,
                              hipStream_t stream) {
    const float* x = (const float*)d_in[0];
    const float* w1 = (const float*)d_in[1];
    const float* a1 = (const float*)d_in[2];
    const float* g1 = (const float*)d_in[3];
    const float* b1 = (const float*)d_in[4];
    const float* m1 = (const float*)d_in[5];
    const float* v1 = (const float*)d_in[6];
    const float* w2 = (const float*)d_in[7];
    const float* a2 = (const float*)d_in[8];
    const float* g2 = (const float*)d_in[9];
    const float* b2 = (const float*)d_in[10];
    const float* m2 = (const float*)d_in[11];
    const float* v2 = (const float*)d_in[12];

    // workspace (~27.1 MB)
    signed char* wf1 = (signed char*)d_ws;             // 589824 B
    signed char* wf2 = wf1 + 589824;                   // 589824 B
    float* wsc1 = (float*)(wf2 + 589824);              // 256 f
    float* wsc2 = wsc1 + 256;                          // 256 f
    float* ep = wsc2 + 256;                            // 1024 f
    unsigned char* xq1 = (unsigned char*)(ep + 1024);  // 12845056 B (packed NHWC)
    unsigned char* hq = xq1 + (size_t)12845056;        // 12845056 B (packed NHWC)

    k_binpack<<<256, 256, 0, stream>>>(w1, wf1, wsc1);
    k_binpack<<<256, 256, 0, stream>>>(w2, wf2, wsc2);
    k_prep<<<1, 256, 0, stream>>>(g1, b1, m1, v1, g2, b2, m2, v2, a1, a2, wsc1, wsc2, ep);
    k_quant_nhwc<<<Bn * Hh * 4, 256, 0, stream>>>(x, xq1, a1);

    // layer 1: packed x -> packed h (BN+ReLU+LSQ(alpha2) fused)
    k_conv<true><<<1024, 256, 0, stream>>>(xq1, wf1, ep, a2, hq, nullptr);
    // layer 2: packed h -> fp32 NCHW out (BN+ReLU)
    k_conv<false><<<1024, 256, 0, stream>>>(hq, wf2, ep + 512, nullptr, nullptr, (float*)d_out);
}

// Round 7
// 179.391 us; speedup vs baseline: 20.7658x; 1.0029x over previous
//
#include <hip/hip_runtime.h>
#include <math.h>

typedef int v4i __attribute__((ext_vector_type(4)));
typedef int v16i __attribute__((ext_vector_type(16)));
typedef unsigned long long u64;

#define Bn 32
#define Cc 256
#define Hh 56
#define Ww 56
#define RSTR (34 * 256)      // LDS bytes per act row: 34 cols x 256 u8 channels
#define ACT_LDS (6 * RSTR)   // 52224 ; x3 blocks = 156672 <= 160 KiB
#define NSTG (6 * 34 * 16)   // 3264 packed u64 staged per block

// ---------------- block-wide sum over 256 threads ----------------
__device__ __forceinline__ float block_sum(float v, float* red) {
#pragma unroll
    for (int off = 32; off > 0; off >>= 1) v += __shfl_down(v, off, 64);
    const int wv = threadIdx.x >> 6;
    __syncthreads();
    if ((threadIdx.x & 63) == 0) red[wv] = v;
    __syncthreads();
    return red[0] + red[1] + red[2] + red[3];
}

// ---- IR-Net binarize + pack sign codes into MFMA-fragment-contiguous layout ----
// v4i unit index: ((tap*8 + c32)*8 + octile)*64 + lane ; lane=(half<<5)|(oc&31)
__global__ __launch_bounds__(256) void k_binpack(const float* __restrict__ w,
                                                 signed char* __restrict__ wf,
                                                 float* __restrict__ wsc) {
    __shared__ float red[4];
    const int o = blockIdx.x;
    const float* wo = w + (size_t)o * 2304;
    const int t = threadIdx.x;
    float v[9];
    float s = 0.f, s2 = 0.f;
#pragma unroll
    for (int i = 0; i < 9; ++i) {
        v[i] = wo[t * 9 + i];
        s += v[i];
        s2 += v[i] * v[i];
    }
    s = block_sum(s, red);
    s2 = block_sum(s2, red);
    const float mu = s * (1.f / 2304.f);
    const float sd = sqrtf(fmaxf(s2 * (1.f / 2304.f) - mu * mu, 0.f));
    float sa = 0.f;
#pragma unroll
    for (int i = 0; i < 9; ++i) sa += fabsf(v[i] - mu);
    sa = block_sum(sa, red);
    if (t == 0) wsc[o] = (sa * (1.f / 2304.f)) / (sd + 1e-5f);
    const int c = t, c32 = c >> 5, hf = (c >> 4) & 1, j = c & 15;
    const int lane = (hf << 5) | (o & 31), octile = o >> 5;
#pragma unroll
    for (int tap = 0; tap < 9; ++tap) {
        const float d = v[tap] - mu;
        const signed char sg = (d > 0.f) ? 1 : ((d < 0.f) ? -1 : 0);
        wf[(size_t)(((tap * 8 + c32) * 8 + octile) * 64 + lane) * 16 + j] = sg;
    }
}

// ---- epilogue params: ep = [f1(256), beta1(256), f2(256), beta2(256)] ----
__global__ void k_prep(const float* __restrict__ g1, const float* __restrict__ b1,
                       const float* __restrict__ m1, const float* __restrict__ v1,
                       const float* __restrict__ g2, const float* __restrict__ b2,
                       const float* __restrict__ m2, const float* __restrict__ v2,
                       const float* __restrict__ a1p, const float* __restrict__ a2p,
                       const float* __restrict__ ws1, const float* __restrict__ ws2,
                       float* __restrict__ ep) {
    const int i = threadIdx.x;
    const float i1 = g1[i] / sqrtf(v1[i] + 1e-5f);
    const float i2 = g2[i] / sqrtf(v2[i] + 1e-5f);
    ep[i] = a1p[0] * ws1[i] * i1;
    ep[256 + i] = b1[i] - m1[i] * i1;
    ep[512 + i] = a2p[0] * ws2[i] * i2;
    ep[768 + i] = b2[i] - m2[i] * i2;
}

// ---- LSQ 4-bit quantize NCHW fp32 -> nibble-packed NHWC ----
// per (n,h,w): 128B = 16 groups x 8B; group g8 byte k = q[g8*16+k] | q[g8*16+k+8]<<4
__global__ __launch_bounds__(256) void k_quant_nhwc(const float* __restrict__ x,
                                                    unsigned char* __restrict__ xq,
                                                    const float* __restrict__ ap) {
    __shared__ unsigned char q[3584];  // [w 56][c 64], dword-swizzled
    const int bid = blockIdx.x;
    const int cg = bid & 3;
    const int h = (bid >> 2) % Hh;
    const int n = bid / (4 * Hh);
    const float a = ap[0];
    const int c0 = cg * 64;
    for (int i = threadIdx.x; i < 3584; i += 256) {
        const int cl = i / 56;
        const int w = i - cl * 56;
        const float v = x[(((size_t)n * Cc + c0 + cl) * Hh + h) * Ww + w];
        const float xs = fminf(fmaxf(v / a, 0.f), 15.f);
        q[w * 64 + (((cl >> 2) ^ (w & 15)) << 2) + (cl & 3)] = (unsigned char)(int)rintf(xs);
    }
    __syncthreads();
    const unsigned int* q32 = (const unsigned int*)q;
    unsigned int* dst = (unsigned int*)xq + ((size_t)(n * Hh + h) * Ww) * 32;
    for (int j = threadIdx.x; j < 448; j += 256) {
        const int w = j >> 3, g8l = (j >> 1) & 3, hf = j & 1;
        const unsigned int lo = q32[w * 16 + ((g8l * 4 + hf) ^ (w & 15))];
        const unsigned int hi = q32[w * 16 + ((g8l * 4 + 2 + hf) ^ (w & 15))];
        dst[w * 32 + (cg * 4 + g8l) * 2 + hf] = lo | (hi << 4);
    }
}

// ---- implicit-GEMM conv, i8 MFMA 32x32x32 ----
// grid 1792 = 32n x 14hb x 2mh x 2oh ; block 256 thr = 4 waves
// wave g: oc [oh*128+g*32, +32) x 4 rows x 32 cols ; acc = 4 x v16i (64 AGPR)
// ~164 regs/wave -> 3 waves/SIMD; LDS 52.2KB -> 3 blocks/CU; c32 order staggered
// per block (integer-exact) to decorrelate co-resident blocks' stalls.
template <bool QOUT>
__global__ __launch_bounds__(256, 3) void k_conv(const unsigned char* __restrict__ xin,
                                                 const signed char* __restrict__ wf,
                                                 const float* __restrict__ ep,
                                                 const float* __restrict__ a2p,
                                                 unsigned char* __restrict__ hq,
                                                 float* __restrict__ yout) {
    __shared__ __align__(16) unsigned char sm[ACT_LDS];  // acts; hbuf aliased later
    const int bid = blockIdx.x;
    const int oh = bid & 1;
    const int mh = (bid >> 1) & 1;
    const int hb = (bid >> 2) % 14;
    const int n = (bid >> 2) / 14;
    const int h0 = hb * 4;
    const int mbase = mh * 32;
    const int tid = threadIdx.x;
    const int boff = bid & 7;

    // ---- stage 6 act rows x 34 cols: packed global -> UNPACKED u8 LDS ----
    // layout: sm[r*RSTR + col*256 + ((t8 ^ (col&15))<<4)] = 16 channels t8*16..+15
    {
        u64 tmp[13];
#pragma unroll
        for (int k = 0; k < 13; ++k) {
            int u = tid + (k << 8);
            u = u > (NSTG - 1) ? (NSTG - 1) : u;
            const int r = u / 544;
            const int rem = u - r * 544;
            const int col = rem >> 4;
            const int t8 = rem & 15;
            int y = h0 - 1 + r;
            int xi = mbase - 1 + col;
            y = y < 0 ? 0 : (y > 55 ? 55 : y);
            xi = xi < 0 ? 0 : (xi > 55 ? 55 : xi);
            tmp[k] = *(const u64*)(xin + ((((size_t)n * Hh + y) * Ww + xi) << 7) + (t8 << 3));
        }
#pragma unroll
        for (int k = 0; k < 13; ++k) {
            const int u = tid + (k << 8);
            if (u < NSTG) {
                const int r = u / 544;
                const int rem = u - r * 544;
                const int col = rem >> 4;
                const int t8 = rem & 15;
                const int y = h0 - 1 + r;
                const int xi = mbase - 1 + col;
                const u64 p = ((unsigned)y < 56u && (unsigned)xi < 56u) ? tmp[k] : 0;
                const u64 lo = p & 0x0F0F0F0F0F0F0F0FULL;
                const u64 hi = (p >> 4) & 0x0F0F0F0F0F0F0F0FULL;
                v4i wv;
                wv[0] = (int)lo;
                wv[1] = (int)(lo >> 32);
                wv[2] = (int)hi;
                wv[3] = (int)(hi >> 32);
                *(v4i*)(sm + r * RSTR + col * 256 + ((t8 ^ (col & 15)) << 4)) = wv;
            }
        }
    }
    __syncthreads();

    const int lane = tid & 63;
    const int g = tid >> 6;
    const int half = lane >> 5;
    const int lm = lane & 31;
    const int octile = oh * 4 + g;

    v16i acc[4] = {};
    const v4i* wpg = (const v4i*)wf + octile * 64 + lane;

    // per-kw swizzle base: addr(kw,c32,ar) = (pkw[kw] ^ (c32<<5)) + ar*RSTR
    int pkw[3];
#pragma unroll
    for (int kw = 0; kw < 3; ++kw) {
        const int col = lm + kw;  // 0..33, in range
        pkw[kw] = (col * 256) ^ (half << 4) ^ ((col & 15) << 4);
    }

#pragma unroll 1
    for (int ii = 0; ii < 8; ++ii) {
        const int c32 = (ii + boff) & 7;  // staggered start; integer-exact reorder
        v4i aw[9];
#pragma unroll
        for (int tap = 0; tap < 9; ++tap) aw[tap] = wpg[(tap * 8 + c32) << 9];
        const int cs = c32 << 5;
#pragma unroll
        for (int kw = 0; kw < 3; ++kw) {
            const unsigned char* bp = sm + (pkw[kw] ^ cs);
            v4i bfr[6];
#pragma unroll
            for (int ar = 0; ar < 6; ++ar)
                bfr[ar] = *(const v4i*)(bp + ar * RSTR);
#pragma unroll
            for (int kh = 0; kh < 3; ++kh) {
#pragma unroll
                for (int r = 0; r < 4; ++r)
                    acc[r] = __builtin_amdgcn_mfma_i32_32x32x32_i8(aw[kh * 3 + kw],
                                                                   bfr[r + kh], acc[r], 0, 0, 0);
            }
        }
    }

    // ---- epilogue ----
    if constexpr (QOUT) {
        __syncthreads();  // acts dead; reuse sm as hbuf [4 r][32 w][16 dwords]
        unsigned int* hb = (unsigned int*)sm;
        const float inva = 1.0f / a2p[0];
        const int oc0w = oh * 128 + g * 32;
        const int d0 = 4 * g + half;
#pragma unroll
        for (int r = 0; r < 4; ++r) {
            const v16i av = acc[r];
            unsigned int pk0 = 0, pk1 = 0;
#pragma unroll
            for (int q = 0; q < 4; ++q) {
                const int oc = oc0w + 4 * half + q;
                const unsigned int c0 = (unsigned int)(int)rintf(
                    fminf(fmaxf(fmaf((float)av[q], ep[oc], ep[256 + oc]), 0.f) * inva, 15.f));
                const unsigned int c1 = (unsigned int)(int)rintf(
                    fminf(fmaxf(fmaf((float)av[4 + q], ep[oc + 8], ep[264 + oc]), 0.f) * inva, 15.f));
                const unsigned int c2 = (unsigned int)(int)rintf(
                    fminf(fmaxf(fmaf((float)av[8 + q], ep[oc + 16], ep[272 + oc]), 0.f) * inva, 15.f));
                const unsigned int c3 = (unsigned int)(int)rintf(
                    fminf(fmaxf(fmaf((float)av[12 + q], ep[oc + 24], ep[280 + oc]), 0.f) * inva, 15.f));
                pk0 |= (c0 | (c1 << 4)) << (8 * q);
                pk1 |= (c2 | (c3 << 4)) << (8 * q);
            }
            const int rb = (r * 32 + lm) * 16;
            hb[rb + (d0 ^ (lm & 15))] = pk0;
            hb[rb + ((d0 + 2) ^ (lm & 15))] = pk1;
        }
        __syncthreads();
        unsigned int* dst = (unsigned int*)hq;
        for (int j = tid; j < 4 * 32 * 16; j += 256) {
            const int rw = j >> 4, dw = j & 15;
            const int r = rw >> 5, wl = rw & 31;
            const int w = mbase + wl;
            if (w < 56)
                dst[((size_t)((n * Hh + h0 + r) * Ww) + w) * 32 + oh * 16 + dw] =
                    hb[(rw << 4) + (dw ^ (wl & 15))];
        }
    } else {
        const int w = mbase + lm;
        if (w < 56) {
            float* dst = yout + (size_t)n * Cc * 3136 + (size_t)h0 * 56 + w;
#pragma unroll
            for (int r = 0; r < 4; ++r) {
                const v16i av = acc[r];
#pragma unroll
                for (int reg = 0; reg < 16; ++reg) {
                    const int oc = oh * 128 + g * 32 + (reg & 3) + 8 * (reg >> 2) + 4 * half;
                    dst[(size_t)oc * 3136 + r * 56] =
                        fmaxf(fmaf((float)av[reg], ep[oc], ep[256 + oc]), 0.f);
                }
            }
        }
    }
}

extern "C" void kernel_launch(void* const* d_in, const int* in_sizes, int n_in,
                              void* d_out, int out_size, void* d_ws, size_t ws_size,
                              hipStream_t stream) {
    const float* x = (const float*)d_in[0];
    const float* w1 = (const float*)d_in[1];
    const float* a1 = (const float*)d_in[2];
    const float* g1 = (const float*)d_in[3];
    const float* b1 = (const float*)d_in[4];
    const float* m1 = (const float*)d_in[5];
    const float* v1 = (const float*)d_in[6];
    const float* w2 = (const float*)d_in[7];
    const float* a2 = (const float*)d_in[8];
    const float* g2 = (const float*)d_in[9];
    const float* b2 = (const float*)d_in[10];
    const float* m2 = (const float*)d_in[11];
    const float* v2 = (const float*)d_in[12];

    // workspace (~27.1 MB)
    signed char* wf1 = (signed char*)d_ws;             // 589824 B
    signed char* wf2 = wf1 + 589824;                   // 589824 B
    float* wsc1 = (float*)(wf2 + 589824);              // 256 f
    float* wsc2 = wsc1 + 256;                          // 256 f
    float* ep = wsc2 + 256;                            // 1024 f
    unsigned char* xq1 = (unsigned char*)(ep + 1024);  // 12845056 B (packed NHWC)
    unsigned char* hq = xq1 + (size_t)12845056;        // 12845056 B (packed NHWC)

    k_binpack<<<256, 256, 0, stream>>>(w1, wf1, wsc1);
    k_binpack<<<256, 256, 0, stream>>>(w2, wf2, wsc2);
    k_prep<<<1, 256, 0, stream>>>(g1, b1, m1, v1, g2, b2, m2, v2, a1, a2, wsc1, wsc2, ep);
    k_quant_nhwc<<<Bn * Hh * 4, 256, 0, stream>>>(x, xq1, a1);

    // layer 1: packed x -> packed h (BN+ReLU+LSQ(alpha2) fused)
    k_conv<true><<<1792, 256, 0, stream>>>(xq1, wf1, ep, a2, hq, nullptr);
    // layer 2: packed h -> fp32 NCHW out (BN+ReLU)
    k_conv<false><<<1792, 256, 0, stream>>>(hq, wf2, ep + 512, nullptr, nullptr, (float*)d_out);
}